// Round 12
// baseline (139.773 us; speedup 1.0000x reference)
//
#include <hip/hip_runtime.h>
#include <hip/hip_bf16.h>

#define N_PTS 4096
#define M_PTS 16384
#define CIN   256
#define CSK   128
#define KDIM  384   // CIN + CSK
#define HDIM  256
#define NSHARD 32
#define SHPTS (N_PTS / NSHARD)   // 128

typedef unsigned int  u32;
typedef unsigned short u16;
typedef unsigned long long u64;
typedef __attribute__((ext_vector_type(8))) short bf16x8;
typedef __attribute__((ext_vector_type(4))) float f32x4;

__device__ __forceinline__ u16 f2bf(float f) {
    union { float f; u32 i; } w; w.f = f;
    u32 x = w.i;
    u32 r = x + 0x7fffu + ((x >> 16) & 1u);   // RTNE
    return (u16)(r >> 16);
}

// strict "better" with lower-index tie-break (stable-sort semantics)
__device__ __forceinline__ bool ltk(float s, int p, float t, int i) {
    return (s < t) || (s == t && p < i);
}
__device__ __forceinline__ void ins3(float s, int p,
                                     float& t0, float& t1, float& t2,
                                     int& i0, int& i1, int& i2) {
    if (ltk(s, p, t2, i2)) {
        if (ltk(s, p, t1, i1)) {
            t2 = t1; i2 = i1;
            if (ltk(s, p, t0, i0)) { t1 = t0; i1 = i0; t0 = s; i0 = p; }
            else                   { t1 = s;  i1 = p; }
        } else { t2 = s; i2 = p; }
    }
}

// value-only sorted-top3 insert: EXACT (min/med3 are rounding-free), 3 VALU.
#define VINS(s, t0, t1, t2)                                               \
    {                                                                     \
        float _o0 = t0, _o1 = t1;                                         \
        t0 = fminf(_o0, (s));                                             \
        t1 = __builtin_amdgcn_fmed3f(_o0, t1, (s));                       \
        t2 = __builtin_amdgcn_fmed3f(_o1, t2, (s));                       \
    }

// ---------------------------------------------------------------------------
// Kernel 0: W1 [384][256] f32 -> W1T [256][384] bf16 (transposed, RTNE)
// ---------------------------------------------------------------------------
__global__ __launch_bounds__(384) void prep_w1t(
    const float* __restrict__ W1, u16* __restrict__ W1T)
{
    const int n = blockIdx.x;       // 256 blocks
    const int k = threadIdx.x;      // 384 threads
    W1T[(size_t)n * KDIM + k] = f2bf(W1[(size_t)k * HDIM + n]);
}

// ---------------------------------------------------------------------------
// Kernel 1: VALUE-ONLY sharded 3-NN scan. 2 queries per thread (one LDS
// broadcast serves both), 2 value-chains per query (ILP). 8 VALU ops/pair.
// Bit-exact fp32 d^2 = (|q|^2 - 2*fma(qz,pz,fma(qy,py,qx*px))) + |p|^2.
// candV[sh*M + m] = (t0,t1,t2,0)  (3 smallest d^2 values in shard, exact)
// ---------------------------------------------------------------------------
__global__ __launch_bounds__(256, 8) void knn_scanV(
    const float* __restrict__ pos,
    const float* __restrict__ pos_skip,
    float4* __restrict__ candV)
{
    __shared__ float4 spts[SHPTS];     // 128 x 16B = 2 KB
    const int tid = threadIdx.x;
    const int sh = blockIdx.y;
    const int pbase = sh * SHPTS;
    const int m0 = blockIdx.x * 512 + tid;
    const int m1 = m0 + 256;

    if (tid < SHPTS) {
        const int i = pbase + tid;
        float px = pos[3 * i], py = pos[3 * i + 1], pz = pos[3 * i + 2];
        float pn = __fadd_rn(__fadd_rn(__fmul_rn(px, px), __fmul_rn(py, py)),
                             __fmul_rn(pz, pz));
        spts[tid] = make_float4(px, py, pz, pn);
    }

    const float qx0 = pos_skip[3 * m0];
    const float qy0 = pos_skip[3 * m0 + 1];
    const float qz0 = pos_skip[3 * m0 + 2];
    const float qn0 = __fadd_rn(__fadd_rn(__fmul_rn(qx0, qx0), __fmul_rn(qy0, qy0)),
                                __fmul_rn(qz0, qz0));
    const float qx1 = pos_skip[3 * m1];
    const float qy1 = pos_skip[3 * m1 + 1];
    const float qz1 = pos_skip[3 * m1 + 2];
    const float qn1 = __fadd_rn(__fadd_rn(__fmul_rn(qx1, qx1), __fmul_rn(qy1, qy1)),
                                __fmul_rn(qz1, qz1));
    __syncthreads();

    // value state: [query][chain]
    float e0[2][2], e1[2][2], e2[2][2];
    #pragma unroll
    for (int q = 0; q < 2; ++q)
        #pragma unroll
        for (int c = 0; c < 2; ++c) {
            e0[q][c] = 3.4e38f; e1[q][c] = 3.4e38f; e2[q][c] = 3.4e38f;
        }

    #pragma unroll 8
    for (int j = 0; j < SHPTS; ++j) {
        float4 v = spts[j];            // wave-uniform broadcast read
        const int c = j & 1;
        {
            float b = __fmaf_rn(qz0, v.z, __fmaf_rn(qy0, v.y, __fmul_rn(qx0, v.x)));
            float s = __fadd_rn(__fmaf_rn(-2.0f, b, qn0), v.w);
            VINS(s, e0[0][c], e1[0][c], e2[0][c]);
        }
        {
            float b = __fmaf_rn(qz1, v.z, __fmaf_rn(qy1, v.y, __fmul_rn(qx1, v.x)));
            float s = __fadd_rn(__fmaf_rn(-2.0f, b, qn1), v.w);
            VINS(s, e0[1][c], e1[1][c], e2[1][c]);
        }
    }

    // merge chain 1 into chain 0 per query (exact value inserts)
    #pragma unroll
    for (int q = 0; q < 2; ++q) {
        VINS(e0[q][1], e0[q][0], e1[q][0], e2[q][0]);
        VINS(e1[q][1], e0[q][0], e1[q][0], e2[q][0]);
        VINS(e2[q][1], e0[q][0], e1[q][0], e2[q][0]);
    }

    candV[(size_t)sh * M_PTS + m0] = make_float4(e0[0][0], e1[0][0], e2[0][0], 0.f);
    candV[(size_t)sh * M_PTS + m1] = make_float4(e0[1][0], e1[1][0], e2[1][0], 0.f);
}

// ---------------------------------------------------------------------------
// Kernel 2: index recovery + weights. ONE WAVE PER QUERY.
// (a) 32-lane butterfly value-merge (each half-wave holds all 32 shards once)
//     -> exact global u0<=u1<=u2,
// (b) shards with shard_min <= u2 qualify (superset of shards holding top-3);
//     each lane accumulates a LANE-LOCAL (value,index) top-3 over the
//     qualifying shards' points (2 pts/lane/shard, no filtering),
// (c) proven 64-lane butterfly ins3 merge (rounds 3-6 pattern) -> exact
//     stable top-3; (value,index) is a strict total order so the result is
//     unique regardless of merge order,
// (d) inverse-distance weights -> nbrw/nbri.
// ---------------------------------------------------------------------------
__global__ __launch_bounds__(256) void knn_recover(
    const float* __restrict__ pos,
    const float* __restrict__ pos_skip,
    const float4* __restrict__ candV,
    float4* __restrict__ nbrw, uint4* __restrict__ nbri)
{
    const int tid  = threadIdx.x;
    const int wave = tid >> 6;
    const int lane = tid & 63;
    const int m = blockIdx.x * 4 + wave;   // 4096 blocks * 4 waves = 16384

    // (a) value merge across the 32 shards (32-lane groups; both halves
    //     hold identical data -> all 64 lanes converge to the same u's)
    const int shl = lane & 31;
    float4 cv = candV[(size_t)shl * M_PTS + m];
    float u0 = cv.x, u1 = cv.y, u2 = cv.z;
    #pragma unroll
    for (int off = 1; off < 32; off <<= 1) {
        float o0 = __shfl_xor(u0, off);
        float o1 = __shfl_xor(u1, off);
        float o2 = __shfl_xor(u2, off);
        VINS(o0, u0, u1, u2);
        VINS(o1, u0, u1, u2);
        VINS(o2, u0, u1, u2);
    }

    const float qx = pos_skip[3 * m];
    const float qy = pos_skip[3 * m + 1];
    const float qz = pos_skip[3 * m + 2];
    const float qn = __fadd_rn(__fadd_rn(__fmul_rn(qx, qx), __fmul_rn(qy, qy)),
                               __fmul_rn(qz, qz));

    // (b) qualifying shards; lane-local (value,index) top-3 accumulation
    u64 qual = __ballot(lane < 32 && cv.x <= u2);

    float t0 = 3.4e38f, t1 = 3.4e38f, t2 = 3.4e38f;
    int   i0 = 0x7fffffff, i1 = 0x7fffffff, i2 = 0x7fffffff;

    while (qual) {
        const int sh = __ffsll(qual) - 1; qual &= qual - 1;
        const int pb = sh * SHPTS;
        #pragma unroll
        for (int it = 0; it < 2; ++it) {
            const int p = pb + it * 64 + lane;
            float px = pos[3 * p], py = pos[3 * p + 1], pz = pos[3 * p + 2];
            float pn = __fadd_rn(__fadd_rn(__fmul_rn(px, px), __fmul_rn(py, py)),
                                 __fmul_rn(pz, pz));
            float b = __fmaf_rn(qz, pz, __fmaf_rn(qy, py, __fmul_rn(qx, px)));
            float s = __fadd_rn(__fmaf_rn(-2.0f, b, qn), pn);
            ins3(s, p, t0, t1, t2, i0, i1, i2);
        }
    }

    // (c) proven 64-lane butterfly (value,index) merge -> all lanes identical
    #pragma unroll
    for (int off = 1; off < 64; off <<= 1) {
        float o0 = __shfl_xor(t0, off);
        float o1 = __shfl_xor(t1, off);
        float o2 = __shfl_xor(t2, off);
        int   j0 = __shfl_xor(i0, off);
        int   j1 = __shfl_xor(i1, off);
        int   j2 = __shfl_xor(i2, off);
        ins3(o0, j0, t0, t1, t2, i0, i1, i2);
        ins3(o1, j1, t0, t1, t2, i0, i1, i2);
        ins3(o2, j2, t0, t1, t2, i0, i1, i2);
    }

    // (d) inverse-distance weights (reference clamps d^2 at 1e-16), fp32
    if (lane == 0) {
        float w0 = __fdiv_rn(1.0f, fmaxf(t0, 1e-16f));
        float w1 = __fdiv_rn(1.0f, fmaxf(t1, 1e-16f));
        float w2 = __fdiv_rn(1.0f, fmaxf(t2, 1e-16f));
        float inv = __fdiv_rn(1.0f, __fadd_rn(__fadd_rn(w0, w1), w2));
        nbrw[m] = make_float4(w0 * inv, w1 * inv, w2 * inv, 0.f);
        nbri[m] = make_uint4((u32)i0, (u32)i1, (u32)i2, 0u);
    }
}

// ---------------------------------------------------------------------------
// Kernel 3 (MFMA): Z = bf16(x) @ bf16(W1[:256,:])   [4096, 256], no bias.
// ---------------------------------------------------------------------------
__global__ __launch_bounds__(256) void gemm_Z(
    const float* __restrict__ x, const u16* __restrict__ W1T,
    float* __restrict__ Z)
{
    __shared__ alignas(16) u16 Bs[64][40];
    const int tid = threadIdx.x;
    const int w = tid >> 6, l = tid & 63;
    const int bm = blockIdx.x * 128;
    const int bn = blockIdx.y * 64;
    const int lr = l & 15, lg = l >> 4;

    f32x4 acc[2][4];
    #pragma unroll
    for (int mt = 0; mt < 2; ++mt)
        #pragma unroll
        for (int nt = 0; nt < 4; ++nt)
            acc[mt][nt] = (f32x4){0.f, 0.f, 0.f, 0.f};

    const int sc = tid >> 2;
    const int sk = (tid & 3) * 8;

    for (int k0 = 0; k0 < CIN; k0 += 32) {
        *reinterpret_cast<bf16x8*>(&Bs[sc][sk]) =
            *reinterpret_cast<const bf16x8*>(&W1T[(size_t)(bn + sc) * KDIM + k0 + sk]);
        __syncthreads();

        bf16x8 af[2];
        #pragma unroll
        for (int mt = 0; mt < 2; ++mt) {
            const float* xp = x + (size_t)(bm + w * 32 + mt * 16 + lr) * CIN + k0 + lg * 8;
            float4 h0 = *reinterpret_cast<const float4*>(xp);
            float4 h1 = *reinterpret_cast<const float4*>(xp + 4);
            af[mt][0] = (short)f2bf(h0.x); af[mt][1] = (short)f2bf(h0.y);
            af[mt][2] = (short)f2bf(h0.z); af[mt][3] = (short)f2bf(h0.w);
            af[mt][4] = (short)f2bf(h1.x); af[mt][5] = (short)f2bf(h1.y);
            af[mt][6] = (short)f2bf(h1.z); af[mt][7] = (short)f2bf(h1.w);
        }
        #pragma unroll
        for (int nt = 0; nt < 4; ++nt) {
            bf16x8 bf = *reinterpret_cast<const bf16x8*>(&Bs[nt * 16 + lr][lg * 8]);
            #pragma unroll
            for (int mt = 0; mt < 2; ++mt)
                acc[mt][nt] = __builtin_amdgcn_mfma_f32_16x16x32_bf16(
                    af[mt], bf, acc[mt][nt], 0, 0, 0);
        }
        __syncthreads();
    }

    #pragma unroll
    for (int nt = 0; nt < 4; ++nt) {
        const int col = bn + nt * 16 + lr;
        #pragma unroll
        for (int mt = 0; mt < 2; ++mt)
            #pragma unroll
            for (int i = 0; i < 4; ++i) {
                const int row = bm + w * 32 + mt * 16 + lg * 4 + i;
                Z[(size_t)row * HDIM + col] = acc[mt][nt][i];
            }
    }
}

// ---------------------------------------------------------------------------
// Kernel 4 (MFMA): S = bf16(x_skip) @ bf16(W1[256:,:]); epilogue fuses the
// knn interpolation: H = relu(S + sum_k w_k Z[i_k] + b1), H stored bf16.
// Gather indices clamped to [0,4095] (defensive: any selection bug becomes
// a measurable absmax, never a page fault).
// ---------------------------------------------------------------------------
__global__ __launch_bounds__(256) void gemm_SH(
    const float* __restrict__ x_skip, const u16* __restrict__ W1T,
    const float* __restrict__ b1, const float* __restrict__ Z,
    const float4* __restrict__ nbrw, const uint4* __restrict__ nbri,
    u16* __restrict__ H)
{
    __shared__ alignas(16) u16 Bs[64][40];
    const int tid = threadIdx.x;
    const int w = tid >> 6, l = tid & 63;
    const int bm = blockIdx.x * 128;
    const int bn = blockIdx.y * 64;
    const int lr = l & 15, lg = l >> 4;

    f32x4 acc[2][4];
    #pragma unroll
    for (int mt = 0; mt < 2; ++mt)
        #pragma unroll
        for (int nt = 0; nt < 4; ++nt)
            acc[mt][nt] = (f32x4){0.f, 0.f, 0.f, 0.f};

    const int sc = tid >> 2;
    const int sk = (tid & 3) * 8;

    for (int k0 = 0; k0 < CSK; k0 += 32) {
        *reinterpret_cast<bf16x8*>(&Bs[sc][sk]) =
            *reinterpret_cast<const bf16x8*>(&W1T[(size_t)(bn + sc) * KDIM + CIN + k0 + sk]);
        __syncthreads();

        bf16x8 af[2];
        #pragma unroll
        for (int mt = 0; mt < 2; ++mt) {
            const float* xp = x_skip + (size_t)(bm + w * 32 + mt * 16 + lr) * CSK + k0 + lg * 8;
            float4 h0 = *reinterpret_cast<const float4*>(xp);
            float4 h1 = *reinterpret_cast<const float4*>(xp + 4);
            af[mt][0] = (short)f2bf(h0.x); af[mt][1] = (short)f2bf(h0.y);
            af[mt][2] = (short)f2bf(h0.z); af[mt][3] = (short)f2bf(h0.w);
            af[mt][4] = (short)f2bf(h1.x); af[mt][5] = (short)f2bf(h1.y);
            af[mt][6] = (short)f2bf(h1.z); af[mt][7] = (short)f2bf(h1.w);
        }
        #pragma unroll
        for (int nt = 0; nt < 4; ++nt) {
            bf16x8 bf = *reinterpret_cast<const bf16x8*>(&Bs[nt * 16 + lr][lg * 8]);
            #pragma unroll
            for (int mt = 0; mt < 2; ++mt)
                acc[mt][nt] = __builtin_amdgcn_mfma_f32_16x16x32_bf16(
                    af[mt], bf, acc[mt][nt], 0, 0, 0);
        }
        __syncthreads();
    }

    // epilogue: blend interpolated Z rows + bias + relu -> H (bf16)
    #pragma unroll
    for (int mt = 0; mt < 2; ++mt) {
        #pragma unroll
        for (int i = 0; i < 4; ++i) {
            const int row = bm + w * 32 + mt * 16 + lg * 4 + i;
            const float4 wv = nbrw[row];
            const uint4  iv = nbri[row];
            const float* z0 = Z + (size_t)(iv.x & 4095u) * HDIM;  // clamp: no OOB
            const float* z1 = Z + (size_t)(iv.y & 4095u) * HDIM;
            const float* z2 = Z + (size_t)(iv.z & 4095u) * HDIM;
            #pragma unroll
            for (int nt = 0; nt < 4; ++nt) {
                const int col = bn + nt * 16 + lr;
                float zb = wv.x * z0[col] + wv.y * z1[col] + wv.z * z2[col];
                float v = acc[mt][nt][i] + zb + b1[col];
                H[(size_t)row * HDIM + col] = f2bf(v > 0.f ? v : 0.f);
            }
        }
    }
}

// ---------------------------------------------------------------------------
// Kernel 5 (MFMA): out = H @ W2 + b2.  H bf16 [16384,256], out f32.
// ---------------------------------------------------------------------------
__global__ __launch_bounds__(256) void gemm2_mfma(
    const u16* __restrict__ H, const float* __restrict__ W2,
    const float* __restrict__ b2, float* __restrict__ out)
{
    __shared__ alignas(16) u16 Bs[64][40];
    const int tid = threadIdx.x;
    const int w = tid >> 6, l = tid & 63;
    const int bm = blockIdx.x * 128;
    const int bn = blockIdx.y * 64;
    const int lr = l & 15, lg = l >> 4;

    f32x4 acc[2][4];
    #pragma unroll
    for (int mt = 0; mt < 2; ++mt)
        #pragma unroll
        for (int nt = 0; nt < 4; ++nt)
            acc[mt][nt] = (f32x4){0.f, 0.f, 0.f, 0.f};

    const int sc = tid >> 2;
    const int sk = (tid & 3) * 8;

    for (int k0 = 0; k0 < HDIM; k0 += 32) {
        #pragma unroll
        for (int j = 0; j < 8; ++j)
            Bs[sc][sk + j] = f2bf(W2[(size_t)(k0 + sk + j) * HDIM + bn + sc]);
        __syncthreads();

        bf16x8 af[2];
        #pragma unroll
        for (int mt = 0; mt < 2; ++mt) {
            const int row = bm + w * 32 + mt * 16 + lr;
            af[mt] = *reinterpret_cast<const bf16x8*>(H + (size_t)row * HDIM + k0 + lg * 8);
        }
        #pragma unroll
        for (int nt = 0; nt < 4; ++nt) {
            bf16x8 bf = *reinterpret_cast<const bf16x8*>(&Bs[nt * 16 + lr][lg * 8]);
            #pragma unroll
            for (int mt = 0; mt < 2; ++mt)
                acc[mt][nt] = __builtin_amdgcn_mfma_f32_16x16x32_bf16(
                    af[mt], bf, acc[mt][nt], 0, 0, 0);
        }
        __syncthreads();
    }

    #pragma unroll
    for (int nt = 0; nt < 4; ++nt) {
        const int col = bn + nt * 16 + lr;
        const float bias = b2[col];
        #pragma unroll
        for (int mt = 0; mt < 2; ++mt)
            #pragma unroll
            for (int i = 0; i < 4; ++i) {
                const int row = bm + w * 32 + mt * 16 + lg * 4 + i;
                out[(size_t)row * HDIM + col] = acc[mt][nt][i] + bias;
            }
    }
}

// ---------------------------------------------------------------------------
extern "C" void kernel_launch(void* const* d_in, const int* in_sizes, int n_in,
                              void* d_out, int out_size, void* d_ws, size_t ws_size,
                              hipStream_t stream) {
    const float* x        = (const float*)d_in[0];
    const float* pos      = (const float*)d_in[1];
    const float* x_skip   = (const float*)d_in[2];
    const float* pos_skip = (const float*)d_in[3];
    const float* W1       = (const float*)d_in[4];
    const float* b1       = (const float*)d_in[5];
    const float* W2       = (const float*)d_in[6];
    const float* b2       = (const float*)d_in[7];

    // d_ws (within proven 12.5 MiB): Hbuf 8M | Z 4M | nbrw 256K | nbri 256K
    u16*    Hbuf = (u16*)d_ws;                               // [16384][256] bf16
    float*  Z    = (float*)((char*)d_ws + (8u << 20));       // [4096][256] f32
    float4* nbrw = (float4*)((char*)d_ws + (12u << 20));
    uint4*  nbri = (uint4*)((char*)d_ws + (12u << 20) + (256u << 10));

    // d_out scratch (all dead before gemm2 writes out):
    float4* candV = (float4*)d_out;                          // [32][16384] f32x4 = 8 MB
    u16*    W1T   = (u16*)((char*)d_out + (14u << 20));      // [256][384] bf16 = 192 KB
    float*  out   = (float*)d_out;

    prep_w1t   <<<256, 384, 0, stream>>>(W1, W1T);
    knn_scanV  <<<dim3(32, NSHARD), 256, 0, stream>>>(pos, pos_skip, candV);
    knn_recover<<<4096, 256, 0, stream>>>(pos, pos_skip, candV, nbrw, nbri);
    gemm_Z     <<<dim3(32, 4), 256, 0, stream>>>(x, W1T, Z);
    gemm_SH    <<<dim3(128, 4), 256, 0, stream>>>(x_skip, W1T, b1, Z, nbrw, nbri, Hbuf);
    gemm2_mfma <<<dim3(128, 4), 256, 0, stream>>>(Hbuf, W2, b2, out);
}